// Round 1
// baseline (622.676 us; speedup 1.0000x reference)
//
#include <hip/hip_runtime.h>
#include <math.h>

#define HH 80
#define WW 80
#define NPIX 6400
#define LL 21
#define NITER 5
#define TJ 256              // j-tile (= blockDim) for bilateral kernels
#define JB (NPIX / TJ)      // 25 tiles cover all pixels

// ---------------- feature precompute: [5][N] = {x/160, y/160, r/3, g/3, b/3}
__global__ void k_feats(const float* __restrict__ img, float* __restrict__ feat) {
    int i = blockIdx.x * blockDim.x + threadIdx.x;
    if (i >= NPIX) return;
    float x = (float)(i % WW), y = (float)(i / WW);
    feat[0 * NPIX + i] = x * (1.0f / 160.0f);
    feat[1 * NPIX + i] = y * (1.0f / 160.0f);
    feat[2 * NPIX + i] = img[0 * NPIX + i] * (1.0f / 3.0f);
    feat[3 * NPIX + i] = img[1 * NPIX + i] * (1.0f / 3.0f);
    feat[4 * NPIX + i] = img[2 * NPIX + i] * (1.0f / 3.0f);
}

// ---------------- spatial norm: rowsum of separable gaussian = Sx(x)*Sy(y)
__global__ void k_norm_sp(float* __restrict__ nsp) {
    int i = blockIdx.x * blockDim.x + threadIdx.x;
    if (i >= NPIX) return;
    float x = (float)(i % WW), y = (float)(i / WW);
    float sx = 0.f, sy = 0.f;
    for (int t = 0; t < WW; t++) { float d = x - (float)t; sx += __expf(-d * d * (1.0f / 18.0f)); }
    for (int t = 0; t < HH; t++) { float d = y - (float)t; sy += __expf(-d * d * (1.0f / 18.0f)); }
    nsp[i] = 1.0f / (sx * sy + 1e-8f);
}

// ---------------- M1 = C @ Wsp, M2 = C @ Wbi  (21x21 each)
__global__ void k_mats(const float* __restrict__ Wsp, const float* __restrict__ Wbi,
                       const float* __restrict__ C, float* __restrict__ M1,
                       float* __restrict__ M2) {
    int t = threadIdx.x;
    if (t >= LL * LL) return;
    int l = t / LL, k = t % LL;
    float a = 0.f, b = 0.f;
    for (int m = 0; m < LL; m++) {
        a += C[l * LL + m] * Wsp[m * LL + k];
        b += C[l * LL + m] * Wbi[m * LL + k];
    }
    M1[t] = a; M2[t] = b;
}

__global__ void k_zero(float* __restrict__ p, int n) {
    int i = blockIdx.x * blockDim.x + threadIdx.x;
    if (i < n) p[i] = 0.f;
}

// ---------------- bilateral row-sum (normalization) partials via atomics
__global__ void k_norm_bi(const float* __restrict__ feat, float* __restrict__ nbacc) {
    __shared__ float ft[5][TJ];
    int tid = threadIdx.x;
    int i = blockIdx.x * TJ + tid;
    int j0 = blockIdx.y * TJ;
    for (int c = 0; c < 5; c++) ft[c][tid] = feat[c * NPIX + j0 + tid];
    __syncthreads();
    float f0 = feat[0 * NPIX + i], f1 = feat[1 * NPIX + i], f2 = feat[2 * NPIX + i],
          f3 = feat[3 * NPIX + i], f4 = feat[4 * NPIX + i];
    float s = 0.f;
    for (int jj = 0; jj < TJ; jj++) {
        float d0 = f0 - ft[0][jj], d1 = f1 - ft[1][jj], d2 = f2 - ft[2][jj],
              d3 = f3 - ft[3][jj], d4 = f4 - ft[4][jj];
        float dd = d0 * d0 + d1 * d1 + d2 * d2 + d3 * d3 + d4 * d4;
        s += __expf(-0.5f * dd);
    }
    atomicAdd(&nbacc[i], s);
}

__global__ void k_norm_fin(const float* __restrict__ nbacc, float* __restrict__ nbi) {
    int i = blockIdx.x * blockDim.x + threadIdx.x;
    if (i < NPIX) nbi[i] = 1.0f / (nbacc[i] + 1e-8f);
}

// ---------------- softmax over labels (axis 0), layout [L][N]
__global__ void k_softmax(const float* __restrict__ in, float* __restrict__ q) {
    int i = blockIdx.x * blockDim.x + threadIdx.x;
    if (i >= NPIX) return;
    float v[LL];
    float m = -1e30f;
    for (int l = 0; l < LL; l++) { v[l] = in[l * NPIX + i]; m = fmaxf(m, v[l]); }
    float s = 0.f;
    for (int l = 0; l < LL; l++) { v[l] = __expf(v[l] - m); s += v[l]; }
    float r = 1.0f / s;
    for (int l = 0; l < LL; l++) q[l * NPIX + i] = v[l] * r;
}

// ---------------- separable spatial filter, x-pass then y-pass
__global__ void k_spat_x(const float* __restrict__ q, float* __restrict__ tmpx) {
    __shared__ float row[WW];
    __shared__ float g[WW];
    int l = blockIdx.x / HH, y = blockIdx.x % HH;
    int t = threadIdx.x;  // 0..79
    row[t] = q[l * NPIX + y * WW + t];
    g[t] = __expf(-(float)(t * t) * (1.0f / 18.0f));
    __syncthreads();
    float s = 0.f;
    for (int xp = 0; xp < WW; xp++) {
        int d = t - xp; d = d < 0 ? -d : d;
        s += g[d] * row[xp];
    }
    tmpx[l * NPIX + y * WW + t] = s;
}

__global__ void k_spat_y(const float* __restrict__ tmpx, float* __restrict__ sp) {
    __shared__ float col[HH];
    __shared__ float g[HH];
    int l = blockIdx.x / WW, x = blockIdx.x % WW;
    int t = threadIdx.x;  // 0..79 (= y)
    col[t] = tmpx[l * NPIX + t * WW + x];
    g[t] = __expf(-(float)(t * t) * (1.0f / 18.0f));
    __syncthreads();
    float s = 0.f;
    for (int yp = 0; yp < HH; yp++) {
        int d = t - yp; d = d < 0 ? -d : d;
        s += g[d] * col[yp];
    }
    sp[l * NPIX + t * WW + x] = s;
}

// ---------------- bilateral message passing: bi[l,i] += sum_j K_bi(i,j) q[l,j]
__global__ void k_bilat(const float* __restrict__ feat, const float* __restrict__ q,
                        float* __restrict__ bi) {
    __shared__ float ft[5][TJ];
    __shared__ float qt[LL][TJ];
    int tid = threadIdx.x;
    int i = blockIdx.x * TJ + tid;
    int j0 = blockIdx.y * TJ;
    for (int c = 0; c < 5; c++) ft[c][tid] = feat[c * NPIX + j0 + tid];
    for (int l = 0; l < LL; l++) qt[l][tid] = q[l * NPIX + j0 + tid];
    __syncthreads();
    float f0 = feat[0 * NPIX + i], f1 = feat[1 * NPIX + i], f2 = feat[2 * NPIX + i],
          f3 = feat[3 * NPIX + i], f4 = feat[4 * NPIX + i];
    float acc[LL];
#pragma unroll
    for (int l = 0; l < LL; l++) acc[l] = 0.f;
    for (int jj = 0; jj < TJ; jj++) {
        float d0 = f0 - ft[0][jj], d1 = f1 - ft[1][jj], d2 = f2 - ft[2][jj],
              d3 = f3 - ft[3][jj], d4 = f4 - ft[4][jj];
        float dd = d0 * d0 + d1 * d1 + d2 * d2 + d3 * d3 + d4 * d4;
        float k = __expf(-0.5f * dd);
#pragma unroll
        for (int l = 0; l < LL; l++) acc[l] += k * qt[l][jj];
    }
#pragma unroll
    for (int l = 0; l < LL; l++) atomicAdd(&bi[l * NPIX + i], acc[l]);
}

// ---------------- combine: dst = unary + M1 @ (sp*nsp) + M2 @ (bi*nbi)
__global__ void k_combine(const float* __restrict__ unary, const float* __restrict__ sp,
                          const float* __restrict__ bi, const float* __restrict__ nsp,
                          const float* __restrict__ nbi, const float* __restrict__ M1,
                          const float* __restrict__ M2, float* __restrict__ dst) {
    __shared__ float m1[LL * LL], m2[LL * LL];
    int tid = threadIdx.x;
    for (int t = tid; t < LL * LL; t += blockDim.x) { m1[t] = M1[t]; m2[t] = M2[t]; }
    __syncthreads();
    int i = blockIdx.x * blockDim.x + tid;
    if (i >= NPIX) return;
    float ns = nsp[i], nb = nbi[i];
    float sv[LL], bv[LL];
    for (int k = 0; k < LL; k++) {
        sv[k] = sp[k * NPIX + i] * ns;
        bv[k] = bi[k * NPIX + i] * nb;
    }
    for (int l = 0; l < LL; l++) {
        float a = unary[l * NPIX + i];
        for (int k = 0; k < LL; k++) a += m1[l * LL + k] * sv[k] + m2[l * LL + k] * bv[k];
        dst[l * NPIX + i] = a;
    }
}

extern "C" void kernel_launch(void* const* d_in, const int* in_sizes, int n_in,
                              void* d_out, int out_size, void* d_ws, size_t ws_size,
                              hipStream_t stream) {
    const float* img   = (const float*)d_in[0];  // [3][N]
    const float* unary = (const float*)d_in[1];  // [L][N]
    const float* Wsp   = (const float*)d_in[2];  // [L][L]
    const float* Wbi   = (const float*)d_in[3];  // [L][L]
    const float* C     = (const float*)d_in[4];  // [L][L]
    float* out = (float*)d_out;                  // [L][N]

    const int LN = LL * NPIX;
    float* w = (float*)d_ws;
    float* cur   = w;              w += LN;
    float* q     = w;              w += LN;
    float* tmpx  = w;              w += LN;
    float* sp    = w;              w += LN;
    float* bi    = w;              w += LN;
    float* feat  = w;              w += 5 * NPIX;
    float* nsp   = w;              w += NPIX;
    float* nbacc = w;              w += NPIX;
    float* nbi   = w;              w += NPIX;
    float* M1    = w;              w += LL * LL;
    float* M2    = w;              w += LL * LL;

    // setup (recomputed every call — same work each time, graph-safe)
    k_feats<<<JB, TJ, 0, stream>>>(img, feat);
    k_norm_sp<<<JB, TJ, 0, stream>>>(nsp);
    k_mats<<<1, 512, 0, stream>>>(Wsp, Wbi, C, M1, M2);
    k_zero<<<(NPIX + 255) / 256, 256, 0, stream>>>(nbacc, NPIX);
    k_norm_bi<<<dim3(JB, JB), TJ, 0, stream>>>(feat, nbacc);
    k_norm_fin<<<JB, TJ, 0, stream>>>(nbacc, nbi);

    for (int it = 0; it < NITER; it++) {
        const float* src = (it == 0) ? unary : cur;
        float* dst = (it == NITER - 1) ? out : cur;
        k_softmax<<<JB, TJ, 0, stream>>>(src, q);
        k_spat_x<<<LL * HH, WW, 0, stream>>>(q, tmpx);
        k_spat_y<<<LL * WW, HH, 0, stream>>>(tmpx, sp);
        k_zero<<<(LN + 255) / 256, 256, 0, stream>>>(bi, LN);
        k_bilat<<<dim3(JB, JB), TJ, 0, stream>>>(feat, q, bi);
        k_combine<<<JB, TJ, 0, stream>>>(unary, sp, bi, nsp, nbi, M1, M2, dst);
    }
}

// Round 2
// 488.985 us; speedup vs baseline: 1.2734x; 1.2734x over previous
//
#include <hip/hip_runtime.h>
#include <math.h>

#define HH 80
#define WW 80
#define NPIX 6400
#define LL 21
#define NITER 5
#define TJ 256              // j-tile (= blockDim) for bilateral kernels
#define JB (NPIX / TJ)      // 25 tiles cover all pixels

// ---------------- pre: feat [5][N], nsp (reciprocal spatial norm), zero nbacc
__global__ void k_pre(const float* __restrict__ img, float* __restrict__ feat,
                      float* __restrict__ nsp, float* __restrict__ nbacc) {
    int i = blockIdx.x * blockDim.x + threadIdx.x;
    if (i >= NPIX) return;
    float x = (float)(i % WW), y = (float)(i / WW);
    feat[0 * NPIX + i] = x * (1.0f / 160.0f);
    feat[1 * NPIX + i] = y * (1.0f / 160.0f);
    feat[2 * NPIX + i] = img[0 * NPIX + i] * (1.0f / 3.0f);
    feat[3 * NPIX + i] = img[1 * NPIX + i] * (1.0f / 3.0f);
    feat[4 * NPIX + i] = img[2 * NPIX + i] * (1.0f / 3.0f);
    float sx = 0.f, sy = 0.f;
    for (int t = 0; t < WW; t++) { float d = x - (float)t; sx += __expf(-d * d * (1.0f / 18.0f)); }
    for (int t = 0; t < HH; t++) { float d = y - (float)t; sy += __expf(-d * d * (1.0f / 18.0f)); }
    nsp[i] = 1.0f / (sx * sy + 1e-8f);
    nbacc[i] = 0.f;
}

// ---------------- M1 = C @ Wsp, M2 = C @ Wbi  (21x21 each)
__global__ void k_mats(const float* __restrict__ Wsp, const float* __restrict__ Wbi,
                       const float* __restrict__ C, float* __restrict__ M1,
                       float* __restrict__ M2) {
    int t = threadIdx.x;
    if (t >= LL * LL) return;
    int l = t / LL, k = t % LL;
    float a = 0.f, b = 0.f;
    for (int m = 0; m < LL; m++) {
        a += C[l * LL + m] * Wsp[m * LL + k];
        b += C[l * LL + m] * Wbi[m * LL + k];
    }
    M1[t] = a; M2[t] = b;
}

// ---------------- bilateral row-sum partials (transposed tile, vector reads)
__global__ void k_norm_bi(const float* __restrict__ feat, float* __restrict__ nbacc) {
    __shared__ float tile[TJ][8];
    int tid = threadIdx.x;
    int i = blockIdx.x * TJ + tid;
    int j0 = blockIdx.y * TJ;
    {
        int j = j0 + tid;
#pragma unroll
        for (int c = 0; c < 5; c++) tile[tid][c] = feat[c * NPIX + j];
    }
    __syncthreads();
    float f0 = feat[0 * NPIX + i], f1 = feat[1 * NPIX + i], f2 = feat[2 * NPIX + i],
          f3 = feat[3 * NPIX + i], f4 = feat[4 * NPIX + i];
    float s = 0.f;
    for (int jj = 0; jj < TJ; jj++) {
        const float* r = &tile[jj][0];
        float4 fa = *(const float4*)r;
        float fb = r[4];
        float d0 = f0 - fa.x, d1 = f1 - fa.y, d2 = f2 - fa.z, d3 = f3 - fa.w, d4 = f4 - fb;
        float dd = d0 * d0 + d1 * d1 + d2 * d2 + d3 * d3 + d4 * d4;
        s += __expf(-0.5f * dd);
    }
    atomicAdd(&nbacc[i], s);
}

// ---------------- initial softmax over labels + zero bi accumulator
__global__ void k_sm0(const float* __restrict__ in, float* __restrict__ q,
                      float* __restrict__ bi) {
    int i = blockIdx.x * blockDim.x + threadIdx.x;
    if (i >= NPIX) return;
    float v[LL];
    float m = -1e30f;
    for (int l = 0; l < LL; l++) { v[l] = in[l * NPIX + i]; m = fmaxf(m, v[l]); }
    float s = 0.f;
    for (int l = 0; l < LL; l++) { v[l] = __expf(v[l] - m); s += v[l]; }
    float r = 1.0f / s;
    for (int l = 0; l < LL; l++) {
        q[l * NPIX + i] = v[l] * r;
        bi[l * NPIX + i] = 0.f;
    }
}

// ---------------- separable spatial filter, x-pass then y-pass
__global__ void k_spat_x(const float* __restrict__ q, float* __restrict__ tmpx) {
    __shared__ float g[WW];
    __shared__ float rows[4][WW];
    int l = blockIdx.x;
    int y = blockIdx.y * 4 + threadIdx.y;
    int x = threadIdx.x;
    int t = threadIdx.y * WW + threadIdx.x;
    if (t < WW) g[t] = __expf(-(float)(t * t) * (1.0f / 18.0f));
    rows[threadIdx.y][x] = q[l * NPIX + y * WW + x];
    __syncthreads();
    float s = 0.f;
    for (int xp = 0; xp < WW; xp++) {
        int d = x - xp; d = d < 0 ? -d : d;
        s += g[d] * rows[threadIdx.y][xp];
    }
    tmpx[l * NPIX + y * WW + x] = s;
}

__global__ void k_spat_y(const float* __restrict__ tmpx, float* __restrict__ sp) {
    __shared__ float g[HH];
    int l = blockIdx.x;
    int y = blockIdx.y * 4 + threadIdx.y;
    int x = threadIdx.x;
    int t = threadIdx.y * WW + threadIdx.x;
    if (t < HH) g[t] = __expf(-(float)(t * t) * (1.0f / 18.0f));
    __syncthreads();
    const float* base = tmpx + l * NPIX + x;
    float s = 0.f;
    for (int yp = 0; yp < HH; yp++) {
        int d = y - yp; d = d < 0 ? -d : d;
        s += g[d] * base[yp * WW];      // coalesced across lanes (x fast)
    }
    sp[l * NPIX + y * WW + x] = s;
}

// ---------------- bilateral message passing (transposed tile, vector reads)
// bi[l,i] += sum_j exp(-0.5||f_i-f_j||^2) q[l,j]
__global__ void k_bilat(const float* __restrict__ feat, const float* __restrict__ q,
                        float* __restrict__ bi) {
    __shared__ float tile[TJ][32];   // [0..4]=f, [8..28]=q, rows 128B-aligned
    int tid = threadIdx.x;
    int i = blockIdx.x * TJ + tid;
    int j0 = blockIdx.y * TJ;
    {
        int j = j0 + tid;
#pragma unroll
        for (int c = 0; c < 5; c++) tile[tid][c] = feat[c * NPIX + j];
#pragma unroll
        for (int l = 0; l < LL; l++) tile[tid][8 + l] = q[l * NPIX + j];
    }
    __syncthreads();
    float f0 = feat[0 * NPIX + i], f1 = feat[1 * NPIX + i], f2 = feat[2 * NPIX + i],
          f3 = feat[3 * NPIX + i], f4 = feat[4 * NPIX + i];
    float acc[LL];
#pragma unroll
    for (int l = 0; l < LL; l++) acc[l] = 0.f;
    for (int jj = 0; jj < TJ; jj++) {
        const float* r = &tile[jj][0];
        float4 fa = *(const float4*)r;
        float fb = r[4];
        float d0 = f0 - fa.x, d1 = f1 - fa.y, d2 = f2 - fa.z, d3 = f3 - fa.w, d4 = f4 - fb;
        float dd = d0 * d0 + d1 * d1 + d2 * d2 + d3 * d3 + d4 * d4;
        float k = __expf(-0.5f * dd);
        float4 q0 = *(const float4*)(r + 8);
        float4 q1 = *(const float4*)(r + 12);
        float4 q2 = *(const float4*)(r + 16);
        float4 q3 = *(const float4*)(r + 20);
        float4 q4 = *(const float4*)(r + 24);
        float  q5 = r[28];
        acc[0] += k * q0.x;  acc[1] += k * q0.y;  acc[2] += k * q0.z;  acc[3] += k * q0.w;
        acc[4] += k * q1.x;  acc[5] += k * q1.y;  acc[6] += k * q1.z;  acc[7] += k * q1.w;
        acc[8] += k * q2.x;  acc[9] += k * q2.y;  acc[10] += k * q2.z; acc[11] += k * q2.w;
        acc[12] += k * q3.x; acc[13] += k * q3.y; acc[14] += k * q3.z; acc[15] += k * q3.w;
        acc[16] += k * q4.x; acc[17] += k * q4.y; acc[18] += k * q4.z; acc[19] += k * q4.w;
        acc[20] += k * q5;
    }
#pragma unroll
    for (int l = 0; l < LL; l++) atomicAdd(&bi[l * NPIX + i], acc[l]);
}

// ---------------- combine (+ fused softmax for non-final iters):
// a = unary + M1 @ (sp*nsp) + M2 @ (bi*nbi);  last ? out=a : (q=softmax(a), bi=0)
__global__ void k_comb(const float* __restrict__ unary, const float* __restrict__ sp,
                       float* __restrict__ bi, const float* __restrict__ nsp,
                       const float* __restrict__ nbacc, const float* __restrict__ M1,
                       const float* __restrict__ M2, float* __restrict__ qout,
                       float* __restrict__ out, int last) {
    __shared__ float m1s[LL * 24];   // rows padded to 24 floats (16B-aligned)
    __shared__ float m2s[LL * 24];
    int tid = threadIdx.x;
    for (int t = tid; t < LL * LL; t += blockDim.x) {
        int l = t / LL, k = t % LL;
        m1s[l * 24 + k] = M1[t];
        m2s[l * 24 + k] = M2[t];
    }
    __syncthreads();
    int i = blockIdx.x * blockDim.x + tid;
    if (i >= NPIX) return;
    float ns = nsp[i];
    float nb = 1.0f / (nbacc[i] + 1e-8f);
    float sv[LL], bv[LL];
    for (int k = 0; k < LL; k++) {
        sv[k] = sp[k * NPIX + i] * ns;
        bv[k] = bi[k * NPIX + i] * nb;
    }
    float a[LL];
    for (int l = 0; l < LL; l++) {
        float acc = unary[l * NPIX + i];
        const float* r1 = &m1s[l * 24];
        const float* r2 = &m2s[l * 24];
#pragma unroll
        for (int k = 0; k < LL; k++) acc += r1[k] * sv[k] + r2[k] * bv[k];
        a[l] = acc;
    }
    if (last) {
        for (int l = 0; l < LL; l++) out[l * NPIX + i] = a[l];
    } else {
        float m = -1e30f;
        for (int l = 0; l < LL; l++) m = fmaxf(m, a[l]);
        float s = 0.f;
        for (int l = 0; l < LL; l++) { a[l] = __expf(a[l] - m); s += a[l]; }
        float r = 1.0f / s;
        for (int l = 0; l < LL; l++) {
            qout[l * NPIX + i] = a[l] * r;
            bi[l * NPIX + i] = 0.f;
        }
    }
}

extern "C" void kernel_launch(void* const* d_in, const int* in_sizes, int n_in,
                              void* d_out, int out_size, void* d_ws, size_t ws_size,
                              hipStream_t stream) {
    const float* img   = (const float*)d_in[0];  // [3][N]
    const float* unary = (const float*)d_in[1];  // [L][N]
    const float* Wsp   = (const float*)d_in[2];  // [L][L]
    const float* Wbi   = (const float*)d_in[3];  // [L][L]
    const float* C     = (const float*)d_in[4];  // [L][L]
    float* out = (float*)d_out;                  // [L][N]

    const int LN = LL * NPIX;
    float* w = (float*)d_ws;
    float* q     = w;              w += LN;
    float* tmpx  = w;              w += LN;
    float* sp    = w;              w += LN;
    float* bi    = w;              w += LN;
    float* feat  = w;              w += 5 * NPIX;
    float* nsp   = w;              w += NPIX;
    float* nbacc = w;              w += NPIX;
    float* M1    = w;              w += LL * LL;
    float* M2    = w;              w += LL * LL;

    k_pre<<<JB, TJ, 0, stream>>>(img, feat, nsp, nbacc);
    k_mats<<<1, 512, 0, stream>>>(Wsp, Wbi, C, M1, M2);
    k_norm_bi<<<dim3(JB, JB), TJ, 0, stream>>>(feat, nbacc);
    k_sm0<<<JB, TJ, 0, stream>>>(unary, q, bi);

    for (int it = 0; it < NITER; it++) {
        int last = (it == NITER - 1);
        k_spat_x<<<dim3(LL, HH / 4), dim3(WW, 4), 0, stream>>>(q, tmpx);
        k_spat_y<<<dim3(LL, HH / 4), dim3(WW, 4), 0, stream>>>(tmpx, sp);
        k_bilat<<<dim3(JB, JB), TJ, 0, stream>>>(feat, q, bi);
        k_comb<<<JB, TJ, 0, stream>>>(unary, sp, bi, nsp, nbacc, M1, M2, q, out, last);
    }
}